// Round 14
// baseline (2254.312 us; speedup 1.0000x reference)
//
#include <hip/hip_runtime.h>
#include <hip/hip_bf16.h>

#define BDIM 64
#define TDIM 360
#define BT (BDIM*TDIM)        // 23040
#define CDIM 128
#define HWSZ 1024
#define SDIM 64
#define G4 512
#define KTOP 160

typedef __hip_bfloat16 bf16;

static __device__ __forceinline__ unsigned int f2bu(float x) {
    bf16 b = __float2bfloat16(x);
    unsigned short u; __builtin_memcpy(&u, &b, 2); return (unsigned int)u;
}
static __device__ __forceinline__ float b2f(bf16 x) { return __bfloat162float(x); }
static __device__ __forceinline__ float bl(unsigned int u) { return __uint_as_float(u << 16); }
static __device__ __forceinline__ float bh(unsigned int u) { return __uint_as_float(u & 0xffff0000u); }
static __device__ __forceinline__ float tanh_fast(float x) {
    float e = __expf(2.0f * x);
    return 1.0f - 2.0f / (e + 1.0f);
}
static __device__ __forceinline__ float sigm(float x) {
    return 1.0f / (1.0f + __expf(-x));
}

// ---- static device workspace ----
__device__ float        g_ArowsF[BT * KTOP];   // [x_emb(32) | in_seq(128)] fp32
__device__ float        g_pre2[BT * G4];       // precomputed non-recurrent gate part
// folded recurrent weights (h-half streamed), bf16 pairs (round 7 layout)
__device__ __align__(16) unsigned int g_wpk2[16 * 1024 * 4];
__device__ float        g_wrecA[128 * G4];     // att-half fold, fp32 (for kA2e)
__device__ __align__(16) unsigned int g_encW2[BDIM * G4 * 32]; // encW[b][n][s2] bf16-pairs
__device__ float        g_encWao[BDIM * 64 * 5];
__device__ float        g_penc[BDIM * SDIM * 64];
__device__ float        g_hw[BT * 192];        // [h(128) | wgt(64)] per (b,t)
__device__ float        g_Wao[256 * 5];
__device__ float        g_bao[5];
__device__ float        g_bias[G4];
__device__ float        g_c0[G4];

// ---- A1: build [x_emb | gathered feature] rows ----
__global__ void kA1(const float* __restrict__ tok, const float* __restrict__ feat,
                    const float* __restrict__ Wemb, const float* __restrict__ bemb) {
    int row  = blockIdx.x * 4 + (threadIdx.x >> 6);
    int lane = threadIdx.x & 63;
    const float* tp = tok + (size_t)row * 4;
    float t0 = tp[0], t1 = tp[1], t2 = tp[2], t3 = tp[3];
    int b = row / TDIM;
    int x = (int)(t0 * 100.0f);
    int y = (int)(t1 * 100.0f);
    x = min(max(x, 0), 31);
    y = min(max(y, 0), 31);
    int idx = y * 32 + x;
    float* out = g_ArowsF + (size_t)row * KTOP;
    if (lane < 32) {
        float e = t0 * Wemb[lane] + t1 * Wemb[32 + lane] +
                  t2 * Wemb[64 + lane] + t3 * Wemb[96 + lane] + bemb[lane];
        out[lane] = e;
    }
    const float* fb = feat + (size_t)b * CDIM * HWSZ + idx;
    out[32 + lane]      = fb[(size_t)lane * HWSZ];
    out[32 + 64 + lane] = fb[(size_t)(64 + lane) * HWSZ];
}

// ---- A2a: fold recurrent weights; h-half packed for streaming, att-half fp32 ----
__global__ void kA2a(const float* __restrict__ Wih, const float* __restrict__ Whh,
                     const float* __restrict__ Waap) {
    __shared__ float sa0[128], sa1[128];
    int p = blockIdx.x, n = threadIdx.x;
    int r0 = 2 * p, r1 = 2 * p + 1;
    if (n < 128)            sa0[n]        = Waap[r0 * 128 + n];
    else if (n < 256)       sa1[n - 128]  = Waap[r1 * 128 + (n - 128)];
    __syncthreads();
    float acc0 = (r0 < 128) ? Whh[r0 * G4 + n] : 0.0f;
    float acc1 = (r1 < 128) ? Whh[r1 * G4 + n] : 0.0f;
    for (int j = 0; j < 128; ++j) {
        float wi = Wih[(160 + j) * G4 + n];
        acc0 += sa0[j] * wi;
        acc1 += sa1[j] * wi;
    }
    int kh = p >> 6, j = p & 63;
    int jblk = j >> 2, jj = j & 3;
    int u = kh * 512 + n;
    g_wpk2[((size_t)jblk * 1024 + u) * 4 + jj] = f2bu(acc0) | (f2bu(acc1) << 16);
    if (p >= 64) {                         // att-half rows, fp32 for kA2e fold
        g_wrecA[(r0 - 128) * G4 + n] = acc0;
        g_wrecA[(r1 - 128) * G4 + n] = acc1;
    }
}

// ---- A2c: bias vectors, c0, Wao, bao ----
__global__ void kA2c(const float* __restrict__ bih, const float* __restrict__ bhh,
                     const float* __restrict__ Wih, const float* __restrict__ Waap,
                     const float* __restrict__ baap, const float* __restrict__ Wout,
                     const float* __restrict__ bout) {
    __shared__ float sb[128];
    int n = threadIdx.x;
    if (n < 128) sb[n] = baap[n];
    __syncthreads();
    g_bias[n] = bih[n] + bhh[n];
    float c0 = 0.0f;
    for (int j = 0; j < 128; ++j) c0 += sb[j] * Wih[(160 + j) * G4 + n];
    g_c0[n] = c0;
    if (n < 256) {
        for (int o = 0; o < 5; ++o) {
            float acc = 0.0f;
            for (int j = 0; j < 128; ++j) acc += Waap[n * 128 + j] * Wout[j * 5 + o];
            g_Wao[n * 5 + o] = acc;
        }
    }
    if (n == 0) {
        for (int o = 0; o < 5; ++o) {
            float acc = bout[o];
            for (int j = 0; j < 128; ++j) acc += sb[j] * Wout[j * 5 + o];
            g_bao[o] = acc;
        }
    }
}

// ---- A2d: p_enc ----
__global__ void kA2d(const float* __restrict__ FH, const float* __restrict__ Wep,
                     const float* __restrict__ bep) {
    __shared__ float sfh[128 * 64];
    int b = blockIdx.x, tid = threadIdx.x;
    for (int i = tid; i < 128 * 64; i += 256) sfh[i] = FH[(size_t)b * 128 * 64 + i];
    __syncthreads();
    int a = tid & 63, sg = tid >> 6;
    float bias = bep[a];
    float acc[16];
#pragma unroll
    for (int i = 0; i < 16; ++i) acc[i] = bias;
    for (int d = 0; d < 128; ++d) {
        float wa = Wep[d * 64 + a];
#pragma unroll
        for (int i = 0; i < 16; ++i) acc[i] += sfh[d * 64 + sg * 16 + i] * wa;
    }
    for (int i = 0; i < 16; ++i)
        g_penc[((size_t)b * 64 + sg * 16 + i) * 64 + a] = acc[i];
}

// ---- A2e: encW[b] = enc[b] @ Wrec_att (bf16 pack), encWao[b] = enc[b] @ Wao_att ----
__global__ void kA2e(const float* __restrict__ FH) {
    __shared__ float encL[64][129];      // enc[s][d], padded
    int b = blockIdx.x, tid = threadIdx.x;
    for (int i = tid; i < 8192; i += 512) {
        int d = i >> 6, s = i & 63;
        encL[s][d] = FH[(size_t)b * 8192 + i];
    }
    __syncthreads();
    int n = tid;
#pragma unroll 1
    for (int sc = 0; sc < 8; ++sc) {
        float acc[8];
#pragma unroll
        for (int j = 0; j < 8; ++j) acc[j] = 0.f;
        for (int d = 0; d < 128; ++d) {
            float wv = g_wrecA[d * G4 + n];
#pragma unroll
            for (int j = 0; j < 8; ++j) acc[j] += encL[sc * 8 + j][d] * wv;
        }
#pragma unroll
        for (int j = 0; j < 4; ++j) {
            int s2 = sc * 4 + j;
            g_encW2[((size_t)b * G4 + n) * 32 + s2] =
                f2bu(acc[2 * j]) | (f2bu(acc[2 * j + 1]) << 16);
        }
    }
    if (tid < 64) {
        for (int o = 0; o < 5; ++o) {
            float acc = 0.f;
            for (int d = 0; d < 128; ++d)
                acc += encL[tid][d] * g_Wao[(128 + d) * 5 + o];
            g_encWao[((size_t)b * 64 + tid) * 5 + o] = acc;
        }
    }
}

// ---- B: pre2 = Arows @ W_ih[0:160] ----
__global__ void __attribute__((amdgpu_flat_work_group_size(512, 512),
                               amdgpu_waves_per_eu(2, 2)))
kB(const float* __restrict__ Wih) {
    int n = threadIdx.x;
    int m0 = blockIdx.x * 8;
    float racc[8];
#pragma unroll
    for (int r = 0; r < 8; ++r) racc[r] = 0.0f;
#pragma unroll 1
    for (int pass = 0; pass < 2; ++pass) {
        float wcol[80];
#pragma unroll
        for (int j = 0; j < 80; ++j) wcol[j] = Wih[(pass * 80 + j) * G4 + n];
#pragma unroll
        for (int r = 0; r < 8; ++r) {
            const float4* rp = (const float4*)(g_ArowsF + (size_t)(m0 + r) * KTOP + pass * 80);
            float a0 = 0.f, a1 = 0.f, a2 = 0.f, a3 = 0.f;
#pragma unroll
            for (int q = 0; q < 20; ++q) {
                float4 v = rp[q];
                a0 += wcol[4 * q + 0] * v.x;
                a1 += wcol[4 * q + 1] * v.y;
                a2 += wcol[4 * q + 2] * v.z;
                a3 += wcol[4 * q + 3] * v.w;
            }
            racc[r] += (a0 + a1) + (a2 + a3);
        }
    }
#pragma unroll
    for (int r = 0; r < 8; ++r)
        g_pre2[(size_t)(m0 + r) * G4 + n] = racc[r];
}

#define CONS1(W, jb) { \
    float4 v0 = vals[2 * (jb)], v1 = vals[2 * (jb) + 1]; \
    acc0 += bl(W.x) * v0.x;  acc1 += bh(W.x) * v0.y; \
    acc0 += bl(W.y) * v0.z;  acc1 += bh(W.y) * v0.w; \
    acc0 += bl(W.z) * v1.x;  acc1 += bh(W.z) * v1.y; \
    acc0 += bl(W.w) * v1.z;  acc1 += bh(W.w) * v1.w; }
#define LDP(R, jb)  R = wp[(jb) * 1024];          // h-half (kh=0)
#define SB __builtin_amdgcn_sched_barrier(0);

// lgkmcnt-only barrier (round 13): weight prefetch stays in flight across it.
#define SYNC() do { __builtin_amdgcn_sched_barrier(0); \
    asm volatile("s_waitcnt lgkmcnt(0)" ::: "memory"); \
    __builtin_amdgcn_s_barrier(); \
    __builtin_amdgcn_sched_barrier(0); } while (0)

// ---- C: sequential recurrence — WAVE-SPECIALIZED, 576 threads (9 waves) ----
// Round-14: rounds 9-13 showed the floor is the 5-6 latency-chained
// barrier-separated tail phases (~1.5-2K cyc each), not any pipe. New split:
//   waves 0-7 (tid<512): h-part of gate dot (thread = gate n)  ─┐ overlapped
//   wave  8   (tid>=512): ENTIRE attention tail in-wave         ─┘
// The tail (atth→scores→softmax) runs on one lockstep wave with no block
// barriers (cross-lane via LDS + in-wave ordering + shfl). 3 barriers/step:
//   [top: h(t-1) ready] hdot(t) ∥ tail→wgt(t-1) ; SYNC ; wgt-dot+gates(t) ;
//   SYNC ; pointwise→h(t) ; SYNC
// Epilogue computes wgt(359). t=0: wgt/c0 contributions guarded to 0.
__global__ void __attribute__((amdgpu_flat_work_group_size(576, 576)))
kC(const float* __restrict__ Walpha,
   const float* __restrict__ balpha,
   const float* __restrict__ bh2a,
   const float* __restrict__ W2a) {
    __shared__ __align__(16) float s_h[128];
    __shared__ float s_c[128];
    __shared__ float s_gates[512];
    __shared__ __align__(16) float s_atth[64];
    __shared__ __align__(8)  float s_wgt[64];
    __shared__ __align__(16) float s_walpha[64];
    __shared__ float s_bh2a[64];
    extern __shared__ __align__(16) char dsm[];
    unsigned int* s_encW  = (unsigned int*)dsm;               // [512][34] u32  69632 B
    float*        s_penc  = (float*)(dsm + 69632);            // [64][66] f32   16896 B
    unsigned int* s_w2aTp = (unsigned int*)(dsm + 69632 + 16896); // [64][66] u32 16896 B

    int tid = threadIdx.x;
    int b = blockIdx.x;
    int n = tid;                                  // gate id (tid<512)

    const uint4* wp = ((const uint4*)g_wpk2) + (tid < 512 ? n : 0);

    uint4 P0,P1,P2,P3,P4,P5,P6,P7,P8,P9,P10,P11,P12,P13,P14,P15;
    LDP(P0,0)  LDP(P1,1)  LDP(P2,2)  LDP(P3,3)
    LDP(P4,4)  LDP(P5,5)  LDP(P6,6)  LDP(P7,7)
    LDP(P8,8)  LDP(P9,9)  LDP(P10,10) LDP(P11,11)
    LDP(P12,12) LDP(P13,13) LDP(P14,14) LDP(P15,15)
    SB

    float bias_r = (tid < 512) ? g_bias[n] : 0.0f;
    float bc_r   = bias_r + ((tid < 512) ? g_c0[n] : 0.0f);

    if (tid < 128) { s_h[tid] = 0.0f; s_c[tid] = 0.0f; }
    if (tid < 64) { s_walpha[tid] = Walpha[tid]; s_bh2a[tid] = bh2a[tid]; }
    for (int i = tid; i < 16384; i += 576) {        // encW (stride 34)
        int row = i >> 5, s2 = i & 31;
        s_encW[row * 34 + s2] = g_encW2[(size_t)b * 16384 + i];
    }
    for (int i = tid; i < 4096; i += 576) {         // penc (stride 66)
        int s = i >> 6, a = i & 63;
        s_penc[s * 66 + a] = g_penc[((size_t)b * 64 + s) * 64 + a];
    }
    for (int i = tid; i < 4096; i += 576) {         // W2a^T packed pairs (stride 66)
        int a = i & 63, k2 = i >> 6;
        s_w2aTp[a * 66 + k2] = f2bu(W2a[(2 * k2) * 64 + a]) |
                               (f2bu(W2a[(2 * k2 + 1) * 64 + a]) << 16);
    }
    float bal = balpha[0];

    const float* pre2p = g_pre2 + (size_t)b * TDIM * G4 + (tid < 512 ? n : 0);
    float* hwp0 = g_hw + (size_t)b * TDIM * 192;

    // whole attention tail for wgt(tprev), on wave 8 only (lane = tid-512)
    auto run_tail = [&](int tprev, bool store_s) {
        int lane = tid - 512;
        // atth[lane] = h . W2a[:,lane] + bh2a
        float ta0 = 0.f, ta1 = 0.f;
        const uint2* wr = (const uint2*)(s_w2aTp + lane * 66);
        const float2* h2 = (const float2*)s_h;
#pragma unroll
        for (int j = 0; j < 32; ++j) {
            uint2 w = wr[j];
            float2 ha = h2[2 * j], hb = h2[2 * j + 1];
            ta0 += bl(w.x) * ha.x;  ta1 += bh(w.x) * ha.y;
            ta0 += bl(w.y) * hb.x;  ta1 += bh(w.y) * hb.y;
        }
        s_atth[lane] = ta0 + ta1 + s_bh2a[lane];
        asm volatile("s_waitcnt lgkmcnt(0)" ::: "memory");   // in-wave: write visible
        __builtin_amdgcn_sched_barrier(0);
        // scores[lane] = sum_a tanh(penc+atth)*walpha
        const float2* pe2 = (const float2*)(s_penc + lane * 66);
        const float4* at4 = (const float4*)s_atth;
        const float4* wl4 = (const float4*)s_walpha;
        float sacc = 0.f;
#pragma unroll
        for (int j = 0; j < 16; ++j) {
            float4 av = at4[j], wv = wl4[j];
            float2 p0 = pe2[2 * j], p1 = pe2[2 * j + 1];
            sacc += tanh_fast(p0.x + av.x) * wv.x;
            sacc += tanh_fast(p0.y + av.y) * wv.y;
            sacc += tanh_fast(p1.x + av.z) * wv.z;
            sacc += tanh_fast(p1.y + av.w) * wv.w;
        }
        float v = sacc + bal;
        float m = v;
#pragma unroll
        for (int off = 32; off > 0; off >>= 1) m = fmaxf(m, __shfl_xor(m, off));
        float e = __expf(v - m);
        float sum = e;
#pragma unroll
        for (int off = 32; off > 0; off >>= 1) sum += __shfl_xor(sum, off);
        float w = e / sum;
        if (store_s) s_wgt[lane] = w;
        hwp0[(size_t)tprev * 192 + 128 + lane] = w;
    };

    SYNC();                               // init LDS visible; h(-1)=0 ready

    for (int t = 0; t < TDIM; ++t) {
        float pre2v = 0.f, acc0 = 0.f, acc1 = 0.f;
        if (tid < 512) {
            pre2v = pre2p[(size_t)t * G4];
            const float4* vals = (const float4*)s_h;
            CONS1(P0,0)  CONS1(P1,1)  CONS1(P2,2)  CONS1(P3,3)
            CONS1(P4,4)  CONS1(P5,5)  CONS1(P6,6)  CONS1(P7,7)
            CONS1(P8,8)  CONS1(P9,9)  CONS1(P10,10) CONS1(P11,11)
            CONS1(P12,12) CONS1(P13,13) CONS1(P14,14) CONS1(P15,15)
            SB
            // prefetch for t+1: stays in flight across SYNCs, lands during tail
            LDP(P0,0)  LDP(P1,1)  LDP(P2,2)  LDP(P3,3)
            LDP(P4,4)  LDP(P5,5)  LDP(P6,6)  LDP(P7,7)
            LDP(P8,8)  LDP(P9,9)  LDP(P10,10) LDP(P11,11)
            LDP(P12,12) LDP(P13,13) LDP(P14,14) LDP(P15,15)
            SB
        } else if (t > 0) {
            run_tail(t - 1, true);        // wgt(t-1) → s_wgt + g_hw
        }
        SYNC();                           // (C) wgt(t-1) ready
        if (tid < 512) {
            float g = acc0 + acc1 + pre2v + (t ? bc_r : bias_r);
            if (t) {                      // wgt-half from LDS-resident encW
                const uint2* er = (const uint2*)(s_encW + n * 34);
                const float2* wg2 = (const float2*)s_wgt;
                float w0 = 0.f, w1 = 0.f;
#pragma unroll
                for (int j = 0; j < 16; ++j) {
                    uint2 ew = er[j];
                    float2 wa = wg2[2 * j], wb = wg2[2 * j + 1];
                    w0 += bl(ew.x) * wa.x;  w1 += bh(ew.x) * wa.y;
                    w0 += bl(ew.y) * wb.x;  w1 += bh(ew.y) * wb.y;
                }
                g += w0 + w1;
            }
            s_gates[n] = g;
        }
        SYNC();                           // (A) gates ready
        if (tid < 128) {                  // LSTM pointwise (i,f,g,o)
            float gi = s_gates[tid];
            float gf = s_gates[tid + 128];
            float gg = s_gates[tid + 256];
            float go = s_gates[tid + 384];
            float c = sigm(gf) * s_c[tid] + sigm(gi) * tanh_fast(gg);
            s_c[tid] = c;
            float h = sigm(go) * tanh_fast(c);
            s_h[tid] = h;
            hwp0[(size_t)t * 192 + tid] = h;
        }
        SYNC();                           // (B) h(t) ready
    }
    if (tid >= 512) run_tail(TDIM - 1, false);   // wgt(359) → g_hw
}

// ---- D: out = h@Wao_h + wgt@encWao[b] + bao ----
__global__ void kD(float* __restrict__ out) {
    int r = blockIdx.x * 4 + (threadIdx.x >> 6);
    int lane = threadIdx.x & 63;
    int b = r / TDIM;
    float acc[5] = {0.f, 0.f, 0.f, 0.f, 0.f};
    if (lane < 48) {
        const float4* hv = (const float4*)(g_hw + (size_t)r * 192);
        float4 v = hv[lane];
        int k0 = lane * 4;
        if (lane < 32) {
#pragma unroll
            for (int o = 0; o < 5; ++o)
                acc[o] = v.x * g_Wao[(k0 + 0) * 5 + o] + v.y * g_Wao[(k0 + 1) * 5 + o] +
                         v.z * g_Wao[(k0 + 2) * 5 + o] + v.w * g_Wao[(k0 + 3) * 5 + o];
        } else {
            int s0 = k0 - 128;
            const float* ew = g_encWao + ((size_t)b * 64 + s0) * 5;
#pragma unroll
            for (int o = 0; o < 5; ++o)
                acc[o] = v.x * ew[o] + v.y * ew[5 + o] + v.z * ew[10 + o] + v.w * ew[15 + o];
        }
    }
#pragma unroll
    for (int off = 32; off > 0; off >>= 1) {
#pragma unroll
        for (int o = 0; o < 5; ++o) acc[o] += __shfl_xor(acc[o], off);
    }
    if (lane == 0) {
#pragma unroll
        for (int o = 0; o < 5; ++o) out[(size_t)r * 5 + o] = acc[o] + g_bao[o];
    }
}

extern "C" void kernel_launch(void* const* d_in, const int* in_sizes, int n_in,
                              void* d_out, int out_size, void* d_ws, size_t ws_size,
                              hipStream_t stream) {
    (void)in_sizes; (void)n_in; (void)d_ws; (void)ws_size; (void)out_size;
    const float* tok  = (const float*)d_in[0];
    const float* feat = (const float*)d_in[1];
    const float* FH   = (const float*)d_in[2];
    const float* Wemb = (const float*)d_in[3];
    const float* bemb = (const float*)d_in[4];
    const float* Wih  = (const float*)d_in[5];
    const float* bih  = (const float*)d_in[6];
    const float* Whh  = (const float*)d_in[7];
    const float* bhh  = (const float*)d_in[8];
    const float* W2a  = (const float*)d_in[9];
    const float* bh2a = (const float*)d_in[10];
    const float* Wal  = (const float*)d_in[11];
    const float* bal  = (const float*)d_in[12];
    const float* Wep  = (const float*)d_in[13];
    const float* bep  = (const float*)d_in[14];
    const float* Waap = (const float*)d_in[15];
    const float* baap = (const float*)d_in[16];
    const float* Wout = (const float*)d_in[17];
    const float* bout = (const float*)d_in[18];
    float* out = (float*)d_out;

    const int kc_dyn_lds = 69632 + 16896 + 16896;    // 103424 B
    (void)hipFuncSetAttribute((const void*)kC,
                              hipFuncAttributeMaxDynamicSharedMemorySize,
                              kc_dyn_lds);

    kA1<<<dim3(BT / 4), dim3(256), 0, stream>>>(tok, feat, Wemb, bemb);
    kA2a<<<dim3(128), dim3(512), 0, stream>>>(Wih, Whh, Waap);
    kA2c<<<dim3(1), dim3(512), 0, stream>>>(bih, bhh, Wih, Waap, baap, Wout, bout);
    kA2d<<<dim3(64), dim3(256), 0, stream>>>(FH, Wep, bep);
    kA2e<<<dim3(BDIM), dim3(512), 0, stream>>>(FH);
    kB<<<dim3(BT / 8), dim3(512), 0, stream>>>(Wih);
    kC<<<dim3(64), dim3(576), kc_dyn_lds, stream>>>(Wal, bal, bh2a, W2a);
    kD<<<dim3(BT / 4), dim3(256), 0, stream>>>(out);
}

// Round 15
// 1662.149 us; speedup vs baseline: 1.3563x; 1.3563x over previous
//
#include <hip/hip_runtime.h>
#include <hip/hip_bf16.h>

#define BDIM 64
#define TDIM 360
#define BT (BDIM*TDIM)        // 23040
#define CDIM 128
#define HWSZ 1024
#define SDIM 64
#define G4 512
#define KTOP 160

typedef __hip_bfloat16 bf16;

static __device__ __forceinline__ unsigned int f2bu(float x) {
    bf16 b = __float2bfloat16(x);
    unsigned short u; __builtin_memcpy(&u, &b, 2); return (unsigned int)u;
}
static __device__ __forceinline__ float b2f(bf16 x) { return __bfloat162float(x); }
static __device__ __forceinline__ float bl(unsigned int u) { return __uint_as_float(u << 16); }
static __device__ __forceinline__ float bh(unsigned int u) { return __uint_as_float(u & 0xffff0000u); }
static __device__ __forceinline__ float tanh_fast(float x) {
    float e = __expf(2.0f * x);
    return 1.0f - 2.0f / (e + 1.0f);
}
static __device__ __forceinline__ float sigm(float x) {
    return 1.0f / (1.0f + __expf(-x));
}

// ---- static device workspace ----
__device__ float        g_ArowsF[BT * KTOP];   // [x_emb(32) | in_seq(128)] fp32
__device__ float        g_pre2[BT * G4];       // precomputed non-recurrent gate part
// folded recurrent weights (h-half streamed once into registers), bf16 pairs
__device__ __align__(16) unsigned int g_wpk2[16 * 1024 * 4];
__device__ float        g_wrecA[128 * G4];     // att-half fold, fp32 (for kA2e)
__device__ __align__(16) unsigned int g_encW2[BDIM * G4 * 32]; // encW[b][n][s2] bf16-pairs
__device__ float        g_encWao[BDIM * 64 * 5];
__device__ float        g_penc[BDIM * SDIM * 64];
__device__ float        g_hw[BT * 192];        // [h(128) | wgt(64)] per (b,t)
__device__ float        g_Wao[256 * 5];
__device__ float        g_bao[5];
__device__ float        g_bias[G4];
__device__ float        g_c0[G4];

// ---- A1: build [x_emb | gathered feature] rows ----
__global__ void kA1(const float* __restrict__ tok, const float* __restrict__ feat,
                    const float* __restrict__ Wemb, const float* __restrict__ bemb) {
    int row  = blockIdx.x * 4 + (threadIdx.x >> 6);
    int lane = threadIdx.x & 63;
    const float* tp = tok + (size_t)row * 4;
    float t0 = tp[0], t1 = tp[1], t2 = tp[2], t3 = tp[3];
    int b = row / TDIM;
    int x = (int)(t0 * 100.0f);
    int y = (int)(t1 * 100.0f);
    x = min(max(x, 0), 31);
    y = min(max(y, 0), 31);
    int idx = y * 32 + x;
    float* out = g_ArowsF + (size_t)row * KTOP;
    if (lane < 32) {
        float e = t0 * Wemb[lane] + t1 * Wemb[32 + lane] +
                  t2 * Wemb[64 + lane] + t3 * Wemb[96 + lane] + bemb[lane];
        out[lane] = e;
    }
    const float* fb = feat + (size_t)b * CDIM * HWSZ + idx;
    out[32 + lane]      = fb[(size_t)lane * HWSZ];
    out[32 + 64 + lane] = fb[(size_t)(64 + lane) * HWSZ];
}

// ---- A2a: fold recurrent weights; h-half packed, att-half fp32 ----
__global__ void kA2a(const float* __restrict__ Wih, const float* __restrict__ Whh,
                     const float* __restrict__ Waap) {
    __shared__ float sa0[128], sa1[128];
    int p = blockIdx.x, n = threadIdx.x;
    int r0 = 2 * p, r1 = 2 * p + 1;
    if (n < 128)            sa0[n]        = Waap[r0 * 128 + n];
    else if (n < 256)       sa1[n - 128]  = Waap[r1 * 128 + (n - 128)];
    __syncthreads();
    float acc0 = (r0 < 128) ? Whh[r0 * G4 + n] : 0.0f;
    float acc1 = (r1 < 128) ? Whh[r1 * G4 + n] : 0.0f;
    for (int j = 0; j < 128; ++j) {
        float wi = Wih[(160 + j) * G4 + n];
        acc0 += sa0[j] * wi;
        acc1 += sa1[j] * wi;
    }
    int kh = p >> 6, j = p & 63;
    int jblk = j >> 2, jj = j & 3;
    int u = kh * 512 + n;
    g_wpk2[((size_t)jblk * 1024 + u) * 4 + jj] = f2bu(acc0) | (f2bu(acc1) << 16);
    if (p >= 64) {                         // att-half rows, fp32 for kA2e fold
        g_wrecA[(r0 - 128) * G4 + n] = acc0;
        g_wrecA[(r1 - 128) * G4 + n] = acc1;
    }
}

// ---- A2c: bias vectors, c0, Wao, bao ----
__global__ void kA2c(const float* __restrict__ bih, const float* __restrict__ bhh,
                     const float* __restrict__ Wih, const float* __restrict__ Waap,
                     const float* __restrict__ baap, const float* __restrict__ Wout,
                     const float* __restrict__ bout) {
    __shared__ float sb[128];
    int n = threadIdx.x;
    if (n < 128) sb[n] = baap[n];
    __syncthreads();
    g_bias[n] = bih[n] + bhh[n];
    float c0 = 0.0f;
    for (int j = 0; j < 128; ++j) c0 += sb[j] * Wih[(160 + j) * G4 + n];
    g_c0[n] = c0;
    if (n < 256) {
        for (int o = 0; o < 5; ++o) {
            float acc = 0.0f;
            for (int j = 0; j < 128; ++j) acc += Waap[n * 128 + j] * Wout[j * 5 + o];
            g_Wao[n * 5 + o] = acc;
        }
    }
    if (n == 0) {
        for (int o = 0; o < 5; ++o) {
            float acc = bout[o];
            for (int j = 0; j < 128; ++j) acc += sb[j] * Wout[j * 5 + o];
            g_bao[o] = acc;
        }
    }
}

// ---- A2d: p_enc ----
__global__ void kA2d(const float* __restrict__ FH, const float* __restrict__ Wep,
                     const float* __restrict__ bep) {
    __shared__ float sfh[128 * 64];
    int b = blockIdx.x, tid = threadIdx.x;
    for (int i = tid; i < 128 * 64; i += 256) sfh[i] = FH[(size_t)b * 128 * 64 + i];
    __syncthreads();
    int a = tid & 63, sg = tid >> 6;
    float bias = bep[a];
    float acc[16];
#pragma unroll
    for (int i = 0; i < 16; ++i) acc[i] = bias;
    for (int d = 0; d < 128; ++d) {
        float wa = Wep[d * 64 + a];
#pragma unroll
        for (int i = 0; i < 16; ++i) acc[i] += sfh[d * 64 + sg * 16 + i] * wa;
    }
    for (int i = 0; i < 16; ++i)
        g_penc[((size_t)b * 64 + sg * 16 + i) * 64 + a] = acc[i];
}

// ---- A2e: encW[b] = enc[b] @ Wrec_att (bf16 pack), encWao[b] = enc[b] @ Wao_att ----
__global__ void kA2e(const float* __restrict__ FH) {
    __shared__ float encL[64][129];      // enc[s][d], padded
    int b = blockIdx.x, tid = threadIdx.x;
    for (int i = tid; i < 8192; i += 512) {
        int d = i >> 6, s = i & 63;
        encL[s][d] = FH[(size_t)b * 8192 + i];
    }
    __syncthreads();
    int n = tid;
#pragma unroll 1
    for (int sc = 0; sc < 8; ++sc) {
        float acc[8];
#pragma unroll
        for (int j = 0; j < 8; ++j) acc[j] = 0.f;
        for (int d = 0; d < 128; ++d) {
            float wv = g_wrecA[d * G4 + n];
#pragma unroll
            for (int j = 0; j < 8; ++j) acc[j] += encL[sc * 8 + j][d] * wv;
        }
#pragma unroll
        for (int j = 0; j < 4; ++j) {
            int s2 = sc * 4 + j;
            g_encW2[((size_t)b * G4 + n) * 32 + s2] =
                f2bu(acc[2 * j]) | (f2bu(acc[2 * j + 1]) << 16);
        }
    }
    if (tid < 64) {
        for (int o = 0; o < 5; ++o) {
            float acc = 0.f;
            for (int d = 0; d < 128; ++d)
                acc += encL[tid][d] * g_Wao[(128 + d) * 5 + o];
            g_encWao[((size_t)b * 64 + tid) * 5 + o] = acc;
        }
    }
}

// ---- B: pre2 = Arows @ W_ih[0:160] ----
__global__ void __attribute__((amdgpu_flat_work_group_size(512, 512),
                               amdgpu_waves_per_eu(2, 2)))
kB(const float* __restrict__ Wih) {
    int n = threadIdx.x;
    int m0 = blockIdx.x * 8;
    float racc[8];
#pragma unroll
    for (int r = 0; r < 8; ++r) racc[r] = 0.0f;
#pragma unroll 1
    for (int pass = 0; pass < 2; ++pass) {
        float wcol[80];
#pragma unroll
        for (int j = 0; j < 80; ++j) wcol[j] = Wih[(pass * 80 + j) * G4 + n];
#pragma unroll
        for (int r = 0; r < 8; ++r) {
            const float4* rp = (const float4*)(g_ArowsF + (size_t)(m0 + r) * KTOP + pass * 80);
            float a0 = 0.f, a1 = 0.f, a2 = 0.f, a3 = 0.f;
#pragma unroll
            for (int q = 0; q < 20; ++q) {
                float4 v = rp[q];
                a0 += wcol[4 * q + 0] * v.x;
                a1 += wcol[4 * q + 1] * v.y;
                a2 += wcol[4 * q + 2] * v.z;
                a3 += wcol[4 * q + 3] * v.w;
            }
            racc[r] += (a0 + a1) + (a2 + a3);
        }
    }
#pragma unroll
    for (int r = 0; r < 8; ++r)
        g_pre2[(size_t)(m0 + r) * G4 + n] = racc[r];
}

#define CONS1(W, jb) { \
    float4 v0 = vals[2 * (jb)], v1 = vals[2 * (jb) + 1]; \
    acc0 += bl(W.x) * v0.x;  acc1 += bh(W.x) * v0.y; \
    acc0 += bl(W.y) * v0.z;  acc1 += bh(W.y) * v0.w; \
    acc0 += bl(W.z) * v1.x;  acc1 += bh(W.z) * v1.y; \
    acc0 += bl(W.w) * v1.z;  acc1 += bh(W.w) * v1.w; }
#define LDP(R, jb)  R = wp[(jb) * 1024];          // h-half (kh=0), column n

// lgkmcnt-only barrier (round 13): global ops stay in flight across it.
#define SYNC() do { __builtin_amdgcn_sched_barrier(0); \
    asm volatile("s_waitcnt lgkmcnt(0)" ::: "memory"); \
    __builtin_amdgcn_s_barrier(); \
    __builtin_amdgcn_sched_barrier(0); } while (0)

// ---- C: sequential recurrence, 512 threads, r12 structure + two fixes ----
// Round-15: (1) PERSISTENT weights: the h-half column (16 uint4 = 64 VGPRs)
// is loaded ONCE before the loop — r13 proved the stream was already hidden,
// so stop re-issuing 16 loads/thread/step; r10/r13 proved 512-thr blocks get
// ~100 VGPRs, which fits 64 weights + working set. (2) gate n = (tid&3)*128
// + (tid>>2): the 4 gates of h-index m land on adjacent lanes 4m..4m+3, so
// LSTM pointwise happens IN-QUAD via 4 __shfl (c in registers) — no s_gates,
// no gates barrier. 4 barriers/step (was 5).
__global__ void __launch_bounds__(512) kC(const float* __restrict__ Walpha,
                                          const float* __restrict__ balpha,
                                          const float* __restrict__ bh2a,
                                          const float* __restrict__ W2a) {
    __shared__ __align__(16) float s_h[128];
    __shared__ __align__(16) float s_atth[64];
    __shared__ float s_scores[64];
    __shared__ __align__(8)  float s_wgt[64];
    __shared__ float s_walpha[64];
    __shared__ float s_bh2a[64];
    extern __shared__ __align__(16) char dsm[];
    unsigned int* s_encW = (unsigned int*)dsm;              // [512][34] u32  69632 B
    float* s_penc = (float*)(dsm + 69632);                  // [64][65] f32   16640 B
    bf16*  s_w2aT = (bf16*)(dsm + 69632 + 16640);           // [64][136] bf16 17408 B

    int tid = threadIdx.x;
    int b = blockIdx.x;
    int lane = tid & 63;
    int qb = lane & ~3;                       // quad base lane
    int n = ((tid & 3) << 7) | (tid >> 2);    // logical gate id
    int m = tid >> 2;                         // h index (0..127)

    // one-time persistent weight load (column n, h-half; never reloaded)
    const uint4* wp = ((const uint4*)g_wpk2) + n;
    uint4 P0,P1,P2,P3,P4,P5,P6,P7,P8,P9,P10,P11,P12,P13,P14,P15;
    LDP(P0,0)  LDP(P1,1)  LDP(P2,2)  LDP(P3,3)
    LDP(P4,4)  LDP(P5,5)  LDP(P6,6)  LDP(P7,7)
    LDP(P8,8)  LDP(P9,9)  LDP(P10,10) LDP(P11,11)
    LDP(P12,12) LDP(P13,13) LDP(P14,14) LDP(P15,15)

    float bias_r = g_bias[n];
    float bc_r   = bias_r + g_c0[n];
    float c_reg  = 0.0f;                      // cell state, in-register (quad-redundant)

    if (tid < 128) s_h[tid] = 0.0f;
    if (tid < 64) { s_walpha[tid] = Walpha[tid]; s_bh2a[tid] = bh2a[tid]; }
    for (int i = tid; i < 16384; i += 512) {        // encW (stride 34)
        int row = i >> 5, s2 = i & 31;
        s_encW[row * 34 + s2] = g_encW2[(size_t)b * 16384 + i];
    }
    for (int i = tid; i < 4096; i += 512) {
        int s = i >> 6, a = i & 63;
        s_penc[s * 65 + a] = g_penc[((size_t)b * 64 + s) * 64 + a];
    }
    for (int i = tid; i < 8192; i += 512) {
        int d = i >> 6, s = i & 63;
        s_w2aT[s * 136 + d] = __float2bfloat16(W2a[i]);
    }
    float bal = balpha[0];

    const float* pre2p = g_pre2 + (size_t)b * TDIM * G4 + n;
    float* hwp0 = g_hw + (size_t)b * TDIM * 192;

    for (int t = 0; t < TDIM; ++t) {
        SYNC();                          // (1) h(t-1), wgt(t-1) ready
        float pre2v = pre2p[(size_t)t * G4];
        float acc0 = 0.f, acc1 = 0.f;
        const float4* vals = (const float4*)s_h;
        CONS1(P0,0)  CONS1(P1,1)  CONS1(P2,2)  CONS1(P3,3)
        CONS1(P4,4)  CONS1(P5,5)  CONS1(P6,6)  CONS1(P7,7)
        CONS1(P8,8)  CONS1(P9,9)  CONS1(P10,10) CONS1(P11,11)
        CONS1(P12,12) CONS1(P13,13) CONS1(P14,14) CONS1(P15,15)
        float g = acc0 + acc1 + pre2v + (t ? bc_r : bias_r);
        if (t) {                          // wgt-half from LDS-resident encW
            const uint2* er = (const uint2*)(s_encW + n * 34);
            const float2* wg2 = (const float2*)s_wgt;
            float w0 = 0.f, w1 = 0.f;
#pragma unroll
            for (int j = 0; j < 16; ++j) {
                uint2 ew = er[j];
                float2 wa = wg2[2 * j], wb = wg2[2 * j + 1];
                w0 += bl(ew.x) * wa.x;  w1 += bh(ew.x) * wa.y;
                w0 += bl(ew.y) * wb.x;  w1 += bh(ew.y) * wb.y;
            }
            g += w0 + w1;
        }
        // LSTM pointwise IN-QUAD: lanes 4m..4m+3 hold gates (i,f,g,o) of h_m
        {
            float gi = __shfl(g, qb + 0);
            float gf = __shfl(g, qb + 1);
            float gg = __shfl(g, qb + 2);
            float go = __shfl(g, qb + 3);
            float c = sigm(gf) * c_reg + sigm(gi) * tanh_fast(gg);
            c_reg = c;
            float h = sigm(go) * tanh_fast(c);
            if ((tid & 3) == 0) {
                s_h[m] = h;
                hwp0[(size_t)t * 192 + m] = h;
            }
        }
        SYNC();                          // (2) h(t) ready
        // att_h[a] = h @ W2a[:,a] + bh2a[a] : 8-lane group per a
        {
            int a = tid >> 3, sub = tid & 7;
            const float4* hv4 = (const float4*)s_h;
            float4 h0 = hv4[4 * sub], h1 = hv4[4 * sub + 1],
                   h2 = hv4[4 * sub + 2], h3 = hv4[4 * sub + 3];
            uint4 w0 = *(const uint4*)&s_w2aT[a * 136 + 16 * sub];
            uint4 w1 = *(const uint4*)&s_w2aT[a * 136 + 16 * sub + 8];
            float acc = bl(w0.x) * h0.x + bh(w0.x) * h0.y +
                        bl(w0.y) * h0.z + bh(w0.y) * h0.w +
                        bl(w0.z) * h1.x + bh(w0.z) * h1.y +
                        bl(w0.w) * h1.z + bh(w0.w) * h1.w +
                        bl(w1.x) * h2.x + bh(w1.x) * h2.y +
                        bl(w1.y) * h2.z + bh(w1.y) * h2.w +
                        bl(w1.z) * h3.x + bh(w1.z) * h3.y +
                        bl(w1.w) * h3.z + bh(w1.w) * h3.w;
            acc += __shfl_xor(acc, 1);
            acc += __shfl_xor(acc, 2);
            acc += __shfl_xor(acc, 4);
            if (sub == 0) s_atth[a] = acc + s_bh2a[a];
        }
        SYNC();                          // (3) atth ready
        // scores[s] = sum_a tanh(p_enc + att_h) * W_alpha : 8 lanes per s
        {
            int ss = tid >> 3, sub = tid & 7;
            float acc = 0.f;
#pragma unroll
            for (int j = 0; j < 8; ++j) {
                int a = sub * 8 + j;
                float xv = s_penc[ss * 65 + a] + s_atth[a];
                acc += tanh_fast(xv) * s_walpha[a];
            }
            acc += __shfl_xor(acc, 1);
            acc += __shfl_xor(acc, 2);
            acc += __shfl_xor(acc, 4);
            if (sub == 0) s_scores[ss] = acc + bal;
        }
        SYNC();                          // (4) scores ready
        if (tid < 64) {                  // softmax → wgt (also stored for kD)
            float v = s_scores[tid];
            float mx = v;
#pragma unroll
            for (int off = 32; off > 0; off >>= 1) mx = fmaxf(mx, __shfl_xor(mx, off));
            float e = __expf(v - mx);
            float sum = e;
#pragma unroll
            for (int off = 32; off > 0; off >>= 1) sum += __shfl_xor(sum, off);
            float w = e / sum;
            s_wgt[tid] = w;
            hwp0[(size_t)t * 192 + 128 + tid] = w;
        }
        // loop-top SYNC covers s_wgt/s_h reuse
    }
}

// ---- D: out = h@Wao_h + wgt@encWao[b] + bao ----
__global__ void kD(float* __restrict__ out) {
    int r = blockIdx.x * 4 + (threadIdx.x >> 6);
    int lane = threadIdx.x & 63;
    int b = r / TDIM;
    float acc[5] = {0.f, 0.f, 0.f, 0.f, 0.f};
    if (lane < 48) {
        const float4* hv = (const float4*)(g_hw + (size_t)r * 192);
        float4 v = hv[lane];
        int k0 = lane * 4;
        if (lane < 32) {
#pragma unroll
            for (int o = 0; o < 5; ++o)
                acc[o] = v.x * g_Wao[(k0 + 0) * 5 + o] + v.y * g_Wao[(k0 + 1) * 5 + o] +
                         v.z * g_Wao[(k0 + 2) * 5 + o] + v.w * g_Wao[(k0 + 3) * 5 + o];
        } else {
            int s0 = k0 - 128;
            const float* ew = g_encWao + ((size_t)b * 64 + s0) * 5;
#pragma unroll
            for (int o = 0; o < 5; ++o)
                acc[o] = v.x * ew[o] + v.y * ew[5 + o] + v.z * ew[10 + o] + v.w * ew[15 + o];
        }
    }
#pragma unroll
    for (int off = 32; off > 0; off >>= 1) {
#pragma unroll
        for (int o = 0; o < 5; ++o) acc[o] += __shfl_xor(acc[o], off);
    }
    if (lane == 0) {
#pragma unroll
        for (int o = 0; o < 5; ++o) out[(size_t)r * 5 + o] = acc[o] + g_bao[o];
    }
}

extern "C" void kernel_launch(void* const* d_in, const int* in_sizes, int n_in,
                              void* d_out, int out_size, void* d_ws, size_t ws_size,
                              hipStream_t stream) {
    (void)in_sizes; (void)n_in; (void)d_ws; (void)ws_size; (void)out_size;
    const float* tok  = (const float*)d_in[0];
    const float* feat = (const float*)d_in[1];
    const float* FH   = (const float*)d_in[2];
    const float* Wemb = (const float*)d_in[3];
    const float* bemb = (const float*)d_in[4];
    const float* Wih  = (const float*)d_in[5];
    const float* bih  = (const float*)d_in[6];
    const float* Whh  = (const float*)d_in[7];
    const float* bhh  = (const float*)d_in[8];
    const float* W2a  = (const float*)d_in[9];
    const float* bh2a = (const float*)d_in[10];
    const float* Wal  = (const float*)d_in[11];
    const float* bal  = (const float*)d_in[12];
    const float* Wep  = (const float*)d_in[13];
    const float* bep  = (const float*)d_in[14];
    const float* Waap = (const float*)d_in[15];
    const float* baap = (const float*)d_in[16];
    const float* Wout = (const float*)d_in[17];
    const float* bout = (const float*)d_in[18];
    float* out = (float*)d_out;

    const int kc_dyn_lds = 69632 + 16640 + 17408;    // 103680 B
    (void)hipFuncSetAttribute((const void*)kC,
                              hipFuncAttributeMaxDynamicSharedMemorySize,
                              kc_dyn_lds);

    kA1<<<dim3(BT / 4), dim3(256), 0, stream>>>(tok, feat, Wemb, bemb);
    kA2a<<<dim3(128), dim3(512), 0, stream>>>(Wih, Whh, Waap);
    kA2c<<<dim3(1), dim3(512), 0, stream>>>(bih, bhh, Wih, Waap, baap, Wout, bout);
    kA2d<<<dim3(64), dim3(256), 0, stream>>>(FH, Wep, bep);
    kA2e<<<dim3(BDIM), dim3(512), 0, stream>>>(FH);
    kB<<<dim3(BT / 8), dim3(512), 0, stream>>>(Wih);
    kC<<<dim3(64), dim3(512), kc_dyn_lds, stream>>>(Wal, bal, bh2a, W2a);
    kD<<<dim3(BT / 4), dim3(256), 0, stream>>>(out);
}

// Round 16
// 1459.203 us; speedup vs baseline: 1.5449x; 1.1391x over previous
//
#include <hip/hip_runtime.h>
#include <hip/hip_bf16.h>

#define BDIM 64
#define TDIM 360
#define BT (BDIM*TDIM)        // 23040
#define CDIM 128
#define HWSZ 1024
#define SDIM 64
#define G4 512
#define KTOP 160

typedef __hip_bfloat16 bf16;

static __device__ __forceinline__ unsigned int f2bu(float x) {
    bf16 b = __float2bfloat16(x);
    unsigned short u; __builtin_memcpy(&u, &b, 2); return (unsigned int)u;
}
static __device__ __forceinline__ float b2f(bf16 x) { return __bfloat162float(x); }
static __device__ __forceinline__ float bl(unsigned int u) { return __uint_as_float(u << 16); }
static __device__ __forceinline__ float bh(unsigned int u) { return __uint_as_float(u & 0xffff0000u); }
static __device__ __forceinline__ float tanh_fast(float x) {
    float e = __expf(2.0f * x);
    return 1.0f - 2.0f / (e + 1.0f);
}
static __device__ __forceinline__ float sigm(float x) {
    return 1.0f / (1.0f + __expf(-x));
}

// ---- static device workspace ----
__device__ float        g_ArowsF[BT * KTOP];   // [x_emb(32) | in_seq(128)] fp32
// pre2 stored PERMUTED: column pl = ((n&127)<<2)|(n>>7) so kC reads at +tid
__device__ float        g_pre2[BT * G4];
// folded recurrent weights (h-half, loaded once into registers), bf16 pairs
__device__ __align__(16) unsigned int g_wpk2[16 * 1024 * 4];
__device__ float        g_wrecA[128 * G4];     // att-half fold, fp32 (for kA2e)
__device__ __align__(16) unsigned int g_encW2[BDIM * G4 * 32]; // encW[b][n][s2] bf16-pairs
__device__ float        g_encWao[BDIM * 64 * 5];
__device__ float        g_penc[BDIM * SDIM * 64];
__device__ float        g_hw[BT * 192];        // [h(128) | wgt(64)] per (b,t)
__device__ float        g_Wao[256 * 5];
__device__ float        g_bao[5];
__device__ float        g_bias[G4];
__device__ float        g_c0[G4];

// ---- A1: build [x_emb | gathered feature] rows ----
__global__ void kA1(const float* __restrict__ tok, const float* __restrict__ feat,
                    const float* __restrict__ Wemb, const float* __restrict__ bemb) {
    int row  = blockIdx.x * 4 + (threadIdx.x >> 6);
    int lane = threadIdx.x & 63;
    const float* tp = tok + (size_t)row * 4;
    float t0 = tp[0], t1 = tp[1], t2 = tp[2], t3 = tp[3];
    int b = row / TDIM;
    int x = (int)(t0 * 100.0f);
    int y = (int)(t1 * 100.0f);
    x = min(max(x, 0), 31);
    y = min(max(y, 0), 31);
    int idx = y * 32 + x;
    float* out = g_ArowsF + (size_t)row * KTOP;
    if (lane < 32) {
        float e = t0 * Wemb[lane] + t1 * Wemb[32 + lane] +
                  t2 * Wemb[64 + lane] + t3 * Wemb[96 + lane] + bemb[lane];
        out[lane] = e;
    }
    const float* fb = feat + (size_t)b * CDIM * HWSZ + idx;
    out[32 + lane]      = fb[(size_t)lane * HWSZ];
    out[32 + 64 + lane] = fb[(size_t)(64 + lane) * HWSZ];
}

// ---- A2a: fold recurrent weights; h-half packed, att-half fp32 ----
__global__ void kA2a(const float* __restrict__ Wih, const float* __restrict__ Whh,
                     const float* __restrict__ Waap) {
    __shared__ float sa0[128], sa1[128];
    int p = blockIdx.x, n = threadIdx.x;
    int r0 = 2 * p, r1 = 2 * p + 1;
    if (n < 128)            sa0[n]        = Waap[r0 * 128 + n];
    else if (n < 256)       sa1[n - 128]  = Waap[r1 * 128 + (n - 128)];
    __syncthreads();
    float acc0 = (r0 < 128) ? Whh[r0 * G4 + n] : 0.0f;
    float acc1 = (r1 < 128) ? Whh[r1 * G4 + n] : 0.0f;
    for (int j = 0; j < 128; ++j) {
        float wi = Wih[(160 + j) * G4 + n];
        acc0 += sa0[j] * wi;
        acc1 += sa1[j] * wi;
    }
    int kh = p >> 6, j = p & 63;
    int jblk = j >> 2, jj = j & 3;
    int u = kh * 512 + n;
    g_wpk2[((size_t)jblk * 1024 + u) * 4 + jj] = f2bu(acc0) | (f2bu(acc1) << 16);
    if (p >= 64) {                         // att-half rows, fp32 for kA2e fold
        g_wrecA[(r0 - 128) * G4 + n] = acc0;
        g_wrecA[(r1 - 128) * G4 + n] = acc1;
    }
}

// ---- A2c: bias vectors, c0, Wao, bao ----
__global__ void kA2c(const float* __restrict__ bih, const float* __restrict__ bhh,
                     const float* __restrict__ Wih, const float* __restrict__ Waap,
                     const float* __restrict__ baap, const float* __restrict__ Wout,
                     const float* __restrict__ bout) {
    __shared__ float sb[128];
    int n = threadIdx.x;
    if (n < 128) sb[n] = baap[n];
    __syncthreads();
    g_bias[n] = bih[n] + bhh[n];
    float c0 = 0.0f;
    for (int j = 0; j < 128; ++j) c0 += sb[j] * Wih[(160 + j) * G4 + n];
    g_c0[n] = c0;
    if (n < 256) {
        for (int o = 0; o < 5; ++o) {
            float acc = 0.0f;
            for (int j = 0; j < 128; ++j) acc += Waap[n * 128 + j] * Wout[j * 5 + o];
            g_Wao[n * 5 + o] = acc;
        }
    }
    if (n == 0) {
        for (int o = 0; o < 5; ++o) {
            float acc = bout[o];
            for (int j = 0; j < 128; ++j) acc += sb[j] * Wout[j * 5 + o];
            g_bao[o] = acc;
        }
    }
}

// ---- A2d: p_enc ----
__global__ void kA2d(const float* __restrict__ FH, const float* __restrict__ Wep,
                     const float* __restrict__ bep) {
    __shared__ float sfh[128 * 64];
    int b = blockIdx.x, tid = threadIdx.x;
    for (int i = tid; i < 128 * 64; i += 256) sfh[i] = FH[(size_t)b * 128 * 64 + i];
    __syncthreads();
    int a = tid & 63, sg = tid >> 6;
    float bias = bep[a];
    float acc[16];
#pragma unroll
    for (int i = 0; i < 16; ++i) acc[i] = bias;
    for (int d = 0; d < 128; ++d) {
        float wa = Wep[d * 64 + a];
#pragma unroll
        for (int i = 0; i < 16; ++i) acc[i] += sfh[d * 64 + sg * 16 + i] * wa;
    }
    for (int i = 0; i < 16; ++i)
        g_penc[((size_t)b * 64 + sg * 16 + i) * 64 + a] = acc[i];
}

// ---- A2e: encW[b] = enc[b] @ Wrec_att (bf16 pack), encWao[b] = enc[b] @ Wao_att ----
__global__ void kA2e(const float* __restrict__ FH) {
    __shared__ float encL[64][129];      // enc[s][d], padded
    int b = blockIdx.x, tid = threadIdx.x;
    for (int i = tid; i < 8192; i += 512) {
        int d = i >> 6, s = i & 63;
        encL[s][d] = FH[(size_t)b * 8192 + i];
    }
    __syncthreads();
    int n = tid;
#pragma unroll 1
    for (int sc = 0; sc < 8; ++sc) {
        float acc[8];
#pragma unroll
        for (int j = 0; j < 8; ++j) acc[j] = 0.f;
        for (int d = 0; d < 128; ++d) {
            float wv = g_wrecA[d * G4 + n];
#pragma unroll
            for (int j = 0; j < 8; ++j) acc[j] += encL[sc * 8 + j][d] * wv;
        }
#pragma unroll
        for (int j = 0; j < 4; ++j) {
            int s2 = sc * 4 + j;
            g_encW2[((size_t)b * G4 + n) * 32 + s2] =
                f2bu(acc[2 * j]) | (f2bu(acc[2 * j + 1]) << 16);
        }
    }
    if (tid < 64) {
        for (int o = 0; o < 5; ++o) {
            float acc = 0.f;
            for (int d = 0; d < 128; ++d)
                acc += encL[tid][d] * g_Wao[(128 + d) * 5 + o];
            g_encWao[((size_t)b * 64 + tid) * 5 + o] = acc;
        }
    }
}

// ---- B: pre2 = Arows @ W_ih[0:160]; stores PERMUTED column for kC ----
__global__ void __attribute__((amdgpu_flat_work_group_size(512, 512),
                               amdgpu_waves_per_eu(2, 2)))
kB(const float* __restrict__ Wih) {
    int n = threadIdx.x;
    int m0 = blockIdx.x * 8;
    int pl = ((n & 127) << 2) | (n >> 7);    // kC thread tid=pl has gate n
    float racc[8];
#pragma unroll
    for (int r = 0; r < 8; ++r) racc[r] = 0.0f;
#pragma unroll 1
    for (int pass = 0; pass < 2; ++pass) {
        float wcol[80];
#pragma unroll
        for (int j = 0; j < 80; ++j) wcol[j] = Wih[(pass * 80 + j) * G4 + n];
#pragma unroll
        for (int r = 0; r < 8; ++r) {
            const float4* rp = (const float4*)(g_ArowsF + (size_t)(m0 + r) * KTOP + pass * 80);
            float a0 = 0.f, a1 = 0.f, a2 = 0.f, a3 = 0.f;
#pragma unroll
            for (int q = 0; q < 20; ++q) {
                float4 v = rp[q];
                a0 += wcol[4 * q + 0] * v.x;
                a1 += wcol[4 * q + 1] * v.y;
                a2 += wcol[4 * q + 2] * v.z;
                a3 += wcol[4 * q + 3] * v.w;
            }
            racc[r] += (a0 + a1) + (a2 + a3);
        }
    }
#pragma unroll
    for (int r = 0; r < 8; ++r)
        g_pre2[(size_t)(m0 + r) * G4 + pl] = racc[r];
}

#define CONS1(W, jb) { \
    float4 v0 = vals[2 * (jb)], v1 = vals[2 * (jb) + 1]; \
    acc0 += bl(W.x) * v0.x;  acc1 += bh(W.x) * v0.y; \
    acc0 += bl(W.y) * v0.z;  acc1 += bh(W.y) * v0.w; \
    acc0 += bl(W.z) * v1.x;  acc1 += bh(W.z) * v1.y; \
    acc0 += bl(W.w) * v1.z;  acc1 += bh(W.w) * v1.w; }
#define LDP(R, jb)  R = wp[(jb) * 1024];          // h-half (kh=0), column n

// lgkmcnt-only barrier (round 13): global ops stay in flight across it.
#define SYNC() do { __builtin_amdgcn_sched_barrier(0); \
    asm volatile("s_waitcnt lgkmcnt(0)" ::: "memory"); \
    __builtin_amdgcn_s_barrier(); \
    __builtin_amdgcn_sched_barrier(0); } while (0)

// ---- C: sequential recurrence, 512 threads (r15 structure, banks fixed) ----
// Round-16: r15's gate permutation n=((tid&3)<<7)|(tid>>2) made quads read
// s_encW rows {m,m+128,m+256,m+384} — 128*34 ≡ 0 mod 32 → same bank, 4-way
// conflict (42.7M conflict cycles). Fix: store encW rows at PERMUTED LDS
// locations (loc(n)=tid) so the hot read is s_encW + tid*34 → banks (2l,2l+1),
// conflict-free; pre2 likewise stored permuted in kB → read at +tid, coalesced.
__global__ void __launch_bounds__(512) kC(const float* __restrict__ Walpha,
                                          const float* __restrict__ balpha,
                                          const float* __restrict__ bh2a,
                                          const float* __restrict__ W2a) {
    __shared__ __align__(16) float s_h[128];
    __shared__ __align__(16) float s_atth[64];
    __shared__ float s_scores[64];
    __shared__ __align__(8)  float s_wgt[64];
    __shared__ float s_walpha[64];
    __shared__ float s_bh2a[64];
    extern __shared__ __align__(16) char dsm[];
    unsigned int* s_encW = (unsigned int*)dsm;              // [512][34] u32  69632 B
    float* s_penc = (float*)(dsm + 69632);                  // [64][65] f32   16640 B
    bf16*  s_w2aT = (bf16*)(dsm + 69632 + 16640);           // [64][136] bf16 17408 B

    int tid = threadIdx.x;
    int b = blockIdx.x;
    int lane = tid & 63;
    int qb = lane & ~3;                       // quad base lane
    int n = ((tid & 3) << 7) | (tid >> 2);    // logical gate id
    int m = tid >> 2;                         // h index (0..127)

    // one-time persistent weight load (column n, h-half; never reloaded)
    const uint4* wp = ((const uint4*)g_wpk2) + n;
    uint4 P0,P1,P2,P3,P4,P5,P6,P7,P8,P9,P10,P11,P12,P13,P14,P15;
    LDP(P0,0)  LDP(P1,1)  LDP(P2,2)  LDP(P3,3)
    LDP(P4,4)  LDP(P5,5)  LDP(P6,6)  LDP(P7,7)
    LDP(P8,8)  LDP(P9,9)  LDP(P10,10) LDP(P11,11)
    LDP(P12,12) LDP(P13,13) LDP(P14,14) LDP(P15,15)

    float bias_r = g_bias[n];
    float bc_r   = bias_r + g_c0[n];
    float c_reg  = 0.0f;                      // cell state, in-register (quad-redundant)

    if (tid < 128) s_h[tid] = 0.0f;
    if (tid < 64) { s_walpha[tid] = Walpha[tid]; s_bh2a[tid] = bh2a[tid]; }
    for (int i = tid; i < 16384; i += 512) {        // encW → LDS at PERMUTED loc
        int row = i >> 5, s2 = i & 31;
        int loc = ((row & 127) << 2) | (row >> 7);  // loc(n(tid)) == tid
        s_encW[loc * 34 + s2] = g_encW2[(size_t)b * 16384 + i];
    }
    for (int i = tid; i < 4096; i += 512) {
        int s = i >> 6, a = i & 63;
        s_penc[s * 65 + a] = g_penc[((size_t)b * 64 + s) * 64 + a];
    }
    for (int i = tid; i < 8192; i += 512) {
        int d = i >> 6, s = i & 63;
        s_w2aT[s * 136 + d] = __float2bfloat16(W2a[i]);
    }
    float bal = balpha[0];

    const float* pre2p = g_pre2 + (size_t)b * TDIM * G4 + tid;   // permuted store → +tid
    float* hwp0 = g_hw + (size_t)b * TDIM * 192;

    for (int t = 0; t < TDIM; ++t) {
        SYNC();                          // (1) h(t-1), wgt(t-1) ready
        float pre2v = pre2p[(size_t)t * G4];
        float acc0 = 0.f, acc1 = 0.f;
        const float4* vals = (const float4*)s_h;
        CONS1(P0,0)  CONS1(P1,1)  CONS1(P2,2)  CONS1(P3,3)
        CONS1(P4,4)  CONS1(P5,5)  CONS1(P6,6)  CONS1(P7,7)
        CONS1(P8,8)  CONS1(P9,9)  CONS1(P10,10) CONS1(P11,11)
        CONS1(P12,12) CONS1(P13,13) CONS1(P14,14) CONS1(P15,15)
        float g = acc0 + acc1 + pre2v + (t ? bc_r : bias_r);
        if (t) {                          // wgt-half from LDS (row tid: conflict-free)
            const uint2* er = (const uint2*)(s_encW + tid * 34);
            const float2* wg2 = (const float2*)s_wgt;
            float w0 = 0.f, w1 = 0.f;
#pragma unroll
            for (int j = 0; j < 16; ++j) {
                uint2 ew = er[j];
                float2 wa = wg2[2 * j], wb = wg2[2 * j + 1];
                w0 += bl(ew.x) * wa.x;  w1 += bh(ew.x) * wa.y;
                w0 += bl(ew.y) * wb.x;  w1 += bh(ew.y) * wb.y;
            }
            g += w0 + w1;
        }
        // LSTM pointwise IN-QUAD: lanes 4m..4m+3 hold gates (i,f,g,o) of h_m
        {
            float gi = __shfl(g, qb + 0);
            float gf = __shfl(g, qb + 1);
            float gg = __shfl(g, qb + 2);
            float go = __shfl(g, qb + 3);
            float c = sigm(gf) * c_reg + sigm(gi) * tanh_fast(gg);
            c_reg = c;
            float h = sigm(go) * tanh_fast(c);
            if ((tid & 3) == 0) {
                s_h[m] = h;
                hwp0[(size_t)t * 192 + m] = h;
            }
        }
        SYNC();                          // (2) h(t) ready
        // att_h[a] = h @ W2a[:,a] + bh2a[a] : 8-lane group per a
        {
            int a = tid >> 3, sub = tid & 7;
            const float4* hv4 = (const float4*)s_h;
            float4 h0 = hv4[4 * sub], h1 = hv4[4 * sub + 1],
                   h2 = hv4[4 * sub + 2], h3 = hv4[4 * sub + 3];
            uint4 w0 = *(const uint4*)&s_w2aT[a * 136 + 16 * sub];
            uint4 w1 = *(const uint4*)&s_w2aT[a * 136 + 16 * sub + 8];
            float acc = bl(w0.x) * h0.x + bh(w0.x) * h0.y +
                        bl(w0.y) * h0.z + bh(w0.y) * h0.w +
                        bl(w0.z) * h1.x + bh(w0.z) * h1.y +
                        bl(w0.w) * h1.z + bh(w0.w) * h1.w +
                        bl(w1.x) * h2.x + bh(w1.x) * h2.y +
                        bl(w1.y) * h2.z + bh(w1.y) * h2.w +
                        bl(w1.z) * h3.x + bh(w1.z) * h3.y +
                        bl(w1.w) * h3.z + bh(w1.w) * h3.w;
            acc += __shfl_xor(acc, 1);
            acc += __shfl_xor(acc, 2);
            acc += __shfl_xor(acc, 4);
            if (sub == 0) s_atth[a] = acc + s_bh2a[a];
        }
        SYNC();                          // (3) atth ready
        // scores[s] = sum_a tanh(p_enc + att_h) * W_alpha : 8 lanes per s
        {
            int ss = tid >> 3, sub = tid & 7;
            float acc = 0.f;
#pragma unroll
            for (int j = 0; j < 8; ++j) {
                int a = sub * 8 + j;
                float xv = s_penc[ss * 65 + a] + s_atth[a];
                acc += tanh_fast(xv) * s_walpha[a];
            }
            acc += __shfl_xor(acc, 1);
            acc += __shfl_xor(acc, 2);
            acc += __shfl_xor(acc, 4);
            if (sub == 0) s_scores[ss] = acc + bal;
        }
        SYNC();                          // (4) scores ready
        if (tid < 64) {                  // softmax → wgt (also stored for kD)
            float v = s_scores[tid];
            float mx = v;
#pragma unroll
            for (int off = 32; off > 0; off >>= 1) mx = fmaxf(mx, __shfl_xor(mx, off));
            float e = __expf(v - mx);
            float sum = e;
#pragma unroll
            for (int off = 32; off > 0; off >>= 1) sum += __shfl_xor(sum, off);
            float w = e / sum;
            s_wgt[tid] = w;
            hwp0[(size_t)t * 192 + 128 + tid] = w;
        }
        // loop-top SYNC covers s_wgt/s_h reuse
    }
}

// ---- D: out = h@Wao_h + wgt@encWao[b] + bao ----
__global__ void kD(float* __restrict__ out) {
    int r = blockIdx.x * 4 + (threadIdx.x >> 6);
    int lane = threadIdx.x & 63;
    int b = r / TDIM;
    float acc[5] = {0.f, 0.f, 0.f, 0.f, 0.f};
    if (lane < 48) {
        const float4* hv = (const float4*)(g_hw + (size_t)r * 192);
        float4 v = hv[lane];
        int k0 = lane * 4;
        if (lane < 32) {
#pragma unroll
            for (int o = 0; o < 5; ++o)
                acc[o] = v.x * g_Wao[(k0 + 0) * 5 + o] + v.y * g_Wao[(k0 + 1) * 5 + o] +
                         v.z * g_Wao[(k0 + 2) * 5 + o] + v.w * g_Wao[(k0 + 3) * 5 + o];
        } else {
            int s0 = k0 - 128;
            const float* ew = g_encWao + ((size_t)b * 64 + s0) * 5;
#pragma unroll
            for (int o = 0; o < 5; ++o)
                acc[o] = v.x * ew[o] + v.y * ew[5 + o] + v.z * ew[10 + o] + v.w * ew[15 + o];
        }
    }
#pragma unroll
    for (int off = 32; off > 0; off >>= 1) {
#pragma unroll
        for (int o = 0; o < 5; ++o) acc[o] += __shfl_xor(acc[o], off);
    }
    if (lane == 0) {
#pragma unroll
        for (int o = 0; o < 5; ++o) out[(size_t)r * 5 + o] = acc[o] + g_bao[o];
    }
}

extern "C" void kernel_launch(void* const* d_in, const int* in_sizes, int n_in,
                              void* d_out, int out_size, void* d_ws, size_t ws_size,
                              hipStream_t stream) {
    (void)in_sizes; (void)n_in; (void)d_ws; (void)ws_size; (void)out_size;
    const float* tok  = (const float*)d_in[0];
    const float* feat = (const float*)d_in[1];
    const float* FH   = (const float*)d_in[2];
    const float* Wemb = (const float*)d_in[3];
    const float* bemb = (const float*)d_in[4];
    const float* Wih  = (const float*)d_in[5];
    const float* bih  = (const float*)d_in[6];
    const float* Whh  = (const float*)d_in[7];
    const float* bhh  = (const float*)d_in[8];
    const float* W2a  = (const float*)d_in[9];
    const float* bh2a = (const float*)d_in[10];
    const float* Wal  = (const float*)d_in[11];
    const float* bal  = (const float*)d_in[12];
    const float* Wep  = (const float*)d_in[13];
    const float* bep  = (const float*)d_in[14];
    const float* Waap = (const float*)d_in[15];
    const float* baap = (const float*)d_in[16];
    const float* Wout = (const float*)d_in[17];
    const float* bout = (const float*)d_in[18];
    float* out = (float*)d_out;

    const int kc_dyn_lds = 69632 + 16640 + 17408;    // 103680 B
    (void)hipFuncSetAttribute((const void*)kC,
                              hipFuncAttributeMaxDynamicSharedMemorySize,
                              kc_dyn_lds);

    kA1<<<dim3(BT / 4), dim3(256), 0, stream>>>(tok, feat, Wemb, bemb);
    kA2a<<<dim3(128), dim3(512), 0, stream>>>(Wih, Whh, Waap);
    kA2c<<<dim3(1), dim3(512), 0, stream>>>(bih, bhh, Wih, Waap, baap, Wout, bout);
    kA2d<<<dim3(64), dim3(256), 0, stream>>>(FH, Wep, bep);
    kA2e<<<dim3(BDIM), dim3(512), 0, stream>>>(FH);
    kB<<<dim3(BT / 8), dim3(512), 0, stream>>>(Wih);
    kC<<<dim3(64), dim3(512), kc_dyn_lds, stream>>>(Wal, bal, bh2a, W2a);
    kD<<<dim3(BT / 4), dim3(256), 0, stream>>>(out);
}

// Round 18
// 1327.686 us; speedup vs baseline: 1.6979x; 1.0991x over previous
//
#include <hip/hip_runtime.h>
#include <hip/hip_bf16.h>

#define BDIM 64
#define TDIM 360
#define BT (BDIM*TDIM)        // 23040
#define CDIM 128
#define HWSZ 1024
#define SDIM 64
#define G4 512
#define KTOP 160

typedef __hip_bfloat16 bf16;
typedef __fp16 h2 __attribute__((ext_vector_type(2)));   // matches cvt_pkrtz/fdot2 native type

static __device__ __forceinline__ unsigned int f2bu(float x) {
    bf16 b = __float2bfloat16(x);
    unsigned short u; __builtin_memcpy(&u, &b, 2); return (unsigned int)u;
}
static __device__ __forceinline__ float bl(unsigned int u) { return __uint_as_float(u << 16); }
static __device__ __forceinline__ float bh(unsigned int u) { return __uint_as_float(u & 0xffff0000u); }
static __device__ __forceinline__ h2 u2h(unsigned int u) {
    h2 r; __builtin_memcpy(&r, &u, 4); return r;
}
static __device__ __forceinline__ unsigned int packh(float a, float b) {
    h2 v = __builtin_amdgcn_cvt_pkrtz(a, b);
    unsigned int u; __builtin_memcpy(&u, &v, 4); return u;
}
static __device__ __forceinline__ float fdot2(unsigned int a, unsigned int b, float c) {
    return __builtin_amdgcn_fdot2(u2h(a), u2h(b), c, false);
}
static __device__ __forceinline__ float tanh_fast(float x) {
    float e = __expf(2.0f * x);
    return 1.0f - 2.0f / (e + 1.0f);
}
static __device__ __forceinline__ float sigm(float x) {
    return 1.0f / (1.0f + __expf(-x));
}

// ---- static device workspace ----
__device__ float        g_ArowsF[BT * KTOP];   // [x_emb(32) | in_seq(128)] fp32
// pre2 stored PERMUTED: column pl = ((n&127)<<2)|(n>>7) so kC reads at +tid
__device__ float        g_pre2[BT * G4];
// folded recurrent weights (h-half), f16 PAIRS, streaming layout
__device__ __align__(16) unsigned int g_wpk2[16 * 1024 * 4];
__device__ float        g_wrecA[128 * G4];     // att-half fold, fp32 (for kA2e)
__device__ __align__(16) unsigned int g_encW2[BDIM * G4 * 32]; // encW[b][n][s2] f16-pairs
__device__ float        g_encWao[BDIM * 64 * 5];
__device__ float        g_penc[BDIM * SDIM * 64];
__device__ float        g_hw[BT * 192];        // [h(128) | wgt(64)] per (b,t)
__device__ float        g_Wao[256 * 5];
__device__ float        g_bao[5];
__device__ float        g_bias[G4];
__device__ float        g_c0[G4];

// ---- A1: build [x_emb | gathered feature] rows ----
__global__ void kA1(const float* __restrict__ tok, const float* __restrict__ feat,
                    const float* __restrict__ Wemb, const float* __restrict__ bemb) {
    int row  = blockIdx.x * 4 + (threadIdx.x >> 6);
    int lane = threadIdx.x & 63;
    const float* tp = tok + (size_t)row * 4;
    float t0 = tp[0], t1 = tp[1], t2 = tp[2], t3 = tp[3];
    int b = row / TDIM;
    int x = (int)(t0 * 100.0f);
    int y = (int)(t1 * 100.0f);
    x = min(max(x, 0), 31);
    y = min(max(y, 0), 31);
    int idx = y * 32 + x;
    float* out = g_ArowsF + (size_t)row * KTOP;
    if (lane < 32) {
        float e = t0 * Wemb[lane] + t1 * Wemb[32 + lane] +
                  t2 * Wemb[64 + lane] + t3 * Wemb[96 + lane] + bemb[lane];
        out[lane] = e;
    }
    const float* fb = feat + (size_t)b * CDIM * HWSZ + idx;
    out[32 + lane]      = fb[(size_t)lane * HWSZ];
    out[32 + 64 + lane] = fb[(size_t)(64 + lane) * HWSZ];
}

// ---- A2a: fold recurrent weights; h-half packed f16, att-half fp32 ----
__global__ void kA2a(const float* __restrict__ Wih, const float* __restrict__ Whh,
                     const float* __restrict__ Waap) {
    __shared__ float sa0[128], sa1[128];
    int p = blockIdx.x, n = threadIdx.x;
    int r0 = 2 * p, r1 = 2 * p + 1;
    if (n < 128)            sa0[n]        = Waap[r0 * 128 + n];
    else if (n < 256)       sa1[n - 128]  = Waap[r1 * 128 + (n - 128)];
    __syncthreads();
    float acc0 = (r0 < 128) ? Whh[r0 * G4 + n] : 0.0f;
    float acc1 = (r1 < 128) ? Whh[r1 * G4 + n] : 0.0f;
    for (int j = 0; j < 128; ++j) {
        float wi = Wih[(160 + j) * G4 + n];
        acc0 += sa0[j] * wi;
        acc1 += sa1[j] * wi;
    }
    int kh = p >> 6, j = p & 63;
    int jblk = j >> 2, jj = j & 3;
    int u = kh * 512 + n;
    g_wpk2[((size_t)jblk * 1024 + u) * 4 + jj] = packh(acc0, acc1);  // f16 pair
    if (p >= 64) {                         // att-half rows, fp32 for kA2e fold
        g_wrecA[(r0 - 128) * G4 + n] = acc0;
        g_wrecA[(r1 - 128) * G4 + n] = acc1;
    }
}

// ---- A2c: bias vectors, c0, Wao, bao ----
__global__ void kA2c(const float* __restrict__ bih, const float* __restrict__ bhh,
                     const float* __restrict__ Wih, const float* __restrict__ Waap,
                     const float* __restrict__ baap, const float* __restrict__ Wout,
                     const float* __restrict__ bout) {
    __shared__ float sb[128];
    int n = threadIdx.x;
    if (n < 128) sb[n] = baap[n];
    __syncthreads();
    g_bias[n] = bih[n] + bhh[n];
    float c0 = 0.0f;
    for (int j = 0; j < 128; ++j) c0 += sb[j] * Wih[(160 + j) * G4 + n];
    g_c0[n] = c0;
    if (n < 256) {
        for (int o = 0; o < 5; ++o) {
            float acc = 0.0f;
            for (int j = 0; j < 128; ++j) acc += Waap[n * 128 + j] * Wout[j * 5 + o];
            g_Wao[n * 5 + o] = acc;
        }
    }
    if (n == 0) {
        for (int o = 0; o < 5; ++o) {
            float acc = bout[o];
            for (int j = 0; j < 128; ++j) acc += sb[j] * Wout[j * 5 + o];
            g_bao[o] = acc;
        }
    }
}

// ---- A2d: p_enc ----
__global__ void kA2d(const float* __restrict__ FH, const float* __restrict__ Wep,
                     const float* __restrict__ bep) {
    __shared__ float sfh[128 * 64];
    int b = blockIdx.x, tid = threadIdx.x;
    for (int i = tid; i < 128 * 64; i += 256) sfh[i] = FH[(size_t)b * 128 * 64 + i];
    __syncthreads();
    int a = tid & 63, sg = tid >> 6;
    float bias = bep[a];
    float acc[16];
#pragma unroll
    for (int i = 0; i < 16; ++i) acc[i] = bias;
    for (int d = 0; d < 128; ++d) {
        float wa = Wep[d * 64 + a];
#pragma unroll
        for (int i = 0; i < 16; ++i) acc[i] += sfh[d * 64 + sg * 16 + i] * wa;
    }
    for (int i = 0; i < 16; ++i)
        g_penc[((size_t)b * 64 + sg * 16 + i) * 64 + a] = acc[i];
}

// ---- A2e: encW[b] = enc[b] @ Wrec_att (f16 pack), encWao[b] = enc[b] @ Wao_att ----
__global__ void kA2e(const float* __restrict__ FH) {
    __shared__ float encL[64][129];      // enc[s][d], padded
    int b = blockIdx.x, tid = threadIdx.x;
    for (int i = tid; i < 8192; i += 512) {
        int d = i >> 6, s = i & 63;
        encL[s][d] = FH[(size_t)b * 8192 + i];
    }
    __syncthreads();
    int n = tid;
#pragma unroll 1
    for (int sc = 0; sc < 8; ++sc) {
        float acc[8];
#pragma unroll
        for (int j = 0; j < 8; ++j) acc[j] = 0.f;
        for (int d = 0; d < 128; ++d) {
            float wv = g_wrecA[d * G4 + n];
#pragma unroll
            for (int j = 0; j < 8; ++j) acc[j] += encL[sc * 8 + j][d] * wv;
        }
#pragma unroll
        for (int j = 0; j < 4; ++j) {
            int s2 = sc * 4 + j;
            g_encW2[((size_t)b * G4 + n) * 32 + s2] = packh(acc[2 * j], acc[2 * j + 1]);
        }
    }
    if (tid < 64) {
        for (int o = 0; o < 5; ++o) {
            float acc = 0.f;
            for (int d = 0; d < 128; ++d)
                acc += encL[tid][d] * g_Wao[(128 + d) * 5 + o];
            g_encWao[((size_t)b * 64 + tid) * 5 + o] = acc;
        }
    }
}

// ---- B: pre2 = Arows @ W_ih[0:160]; stores PERMUTED column for kC ----
__global__ void __attribute__((amdgpu_flat_work_group_size(512, 512),
                               amdgpu_waves_per_eu(2, 2)))
kB(const float* __restrict__ Wih) {
    int n = threadIdx.x;
    int m0 = blockIdx.x * 8;
    int pl = ((n & 127) << 2) | (n >> 7);    // kC thread tid=pl has gate n
    float racc[8];
#pragma unroll
    for (int r = 0; r < 8; ++r) racc[r] = 0.0f;
#pragma unroll 1
    for (int pass = 0; pass < 2; ++pass) {
        float wcol[80];
#pragma unroll
        for (int j = 0; j < 80; ++j) wcol[j] = Wih[(pass * 80 + j) * G4 + n];
#pragma unroll
        for (int r = 0; r < 8; ++r) {
            const float4* rp = (const float4*)(g_ArowsF + (size_t)(m0 + r) * KTOP + pass * 80);
            float a0 = 0.f, a1 = 0.f, a2 = 0.f, a3 = 0.f;
#pragma unroll
            for (int q = 0; q < 20; ++q) {
                float4 v = rp[q];
                a0 += wcol[4 * q + 0] * v.x;
                a1 += wcol[4 * q + 1] * v.y;
                a2 += wcol[4 * q + 2] * v.z;
                a3 += wcol[4 * q + 3] * v.w;
            }
            racc[r] += (a0 + a1) + (a2 + a3);
        }
    }
#pragma unroll
    for (int r = 0; r < 8; ++r)
        g_pre2[(size_t)(m0 + r) * G4 + pl] = racc[r];
}

// f16-dot2 consume: uint4 W = 4 f16-pairs vs h-pairs hvals4[jb]; 8 MACs in 4 inst
#define CONS1f(W, jb) { uint4 hp = hvals4[jb]; \
    acc0 = fdot2(W.x, hp.x, acc0); \
    acc1 = fdot2(W.y, hp.y, acc1); \
    acc0 = fdot2(W.z, hp.z, acc0); \
    acc1 = fdot2(W.w, hp.w, acc1); }
#define LDP(R, jb)  R = wp[(jb) * 1024];          // h-half (kh=0), column n

// lgkmcnt-only barrier (round 13): global ops stay in flight across it.
#define SYNC() do { __builtin_amdgcn_sched_barrier(0); \
    asm volatile("s_waitcnt lgkmcnt(0)" ::: "memory"); \
    __builtin_amdgcn_s_barrier(); \
    __builtin_amdgcn_sched_barrier(0); } while (0)

// ---- C: sequential recurrence, 512 threads (r16 structure, f16 dot2 math) ----
// Round-18 = round-17 with the h2 typedef fixed (__fp16 vector, the builtin's
// native type). r16 PMC showed ~975 VALU inst/thread/step, half bf16-unpack
// shadow ops; all three dots now use v_dot2_f32_f16 on packed f16 pairs.
__global__ void __launch_bounds__(512) kC(const float* __restrict__ Walpha,
                                          const float* __restrict__ balpha,
                                          const float* __restrict__ bh2a,
                                          const float* __restrict__ W2a) {
    __shared__ __align__(16) unsigned int s_h2[64];    // h packed f16x2
    __shared__ __align__(16) float s_atth[64];
    __shared__ float s_scores[64];
    __shared__ __align__(16) unsigned int s_wgt2[32];  // wgt packed f16x2
    __shared__ __align__(16) float s_walpha[64];
    __shared__ float s_bh2a[64];
    extern __shared__ __align__(16) char dsm[];
    unsigned int* s_encW  = (unsigned int*)dsm;             // [512][34] u32  69632 B
    float*        s_penc  = (float*)(dsm + 69632);          // [64][65] f32   16640 B
    unsigned int* s_w2aTp = (unsigned int*)(dsm + 69632 + 16640); // [64][68] u32 17408 B

    int tid = threadIdx.x;
    int b = blockIdx.x;
    int lane = tid & 63;
    int qb = lane & ~3;                       // quad base lane
    int n = ((tid & 3) << 7) | (tid >> 2);    // logical gate id
    int m = tid >> 2;                         // h index (0..127)

    // one-time persistent weight load (column n, h-half f16 pairs)
    const uint4* wp = ((const uint4*)g_wpk2) + n;
    uint4 P0,P1,P2,P3,P4,P5,P6,P7,P8,P9,P10,P11,P12,P13,P14,P15;
    LDP(P0,0)  LDP(P1,1)  LDP(P2,2)  LDP(P3,3)
    LDP(P4,4)  LDP(P5,5)  LDP(P6,6)  LDP(P7,7)
    LDP(P8,8)  LDP(P9,9)  LDP(P10,10) LDP(P11,11)
    LDP(P12,12) LDP(P13,13) LDP(P14,14) LDP(P15,15)

    float bias_r = g_bias[n];
    float bc_r   = bias_r + g_c0[n];
    float c_reg  = 0.0f;                      // cell state, in-register (quad-redundant)

    if (tid < 64) { s_h2[tid] = 0u; s_walpha[tid] = Walpha[tid]; s_bh2a[tid] = bh2a[tid]; }
    for (int i = tid; i < 16384; i += 512) {        // encW → LDS at PERMUTED loc
        int row = i >> 5, s2 = i & 31;
        int loc = ((row & 127) << 2) | (row >> 7);  // loc(n(tid)) == tid
        s_encW[loc * 34 + s2] = g_encW2[(size_t)b * 16384 + i];
    }
    for (int i = tid; i < 4096; i += 512) {
        int s = i >> 6, a = i & 63;
        s_penc[s * 65 + a] = g_penc[((size_t)b * 64 + s) * 64 + a];
    }
    for (int i = tid; i < 4096; i += 512) {         // W2a^T packed f16 pairs over k
        int a = i & 63, k2 = i >> 6;
        s_w2aTp[a * 68 + k2] = packh(W2a[(2 * k2) * 64 + a], W2a[(2 * k2 + 1) * 64 + a]);
    }
    float bal = balpha[0];

    const float* pre2p = g_pre2 + (size_t)b * TDIM * G4 + tid;   // permuted store → +tid
    float* hwp0 = g_hw + (size_t)b * TDIM * 192;

    for (int t = 0; t < TDIM; ++t) {
        SYNC();                          // (1) h(t-1), wgt(t-1) ready
        float pre2v = pre2p[(size_t)t * G4];
        float acc0 = 0.f, acc1 = 0.f;
        const uint4* hvals4 = (const uint4*)s_h2;
        CONS1f(P0,0)  CONS1f(P1,1)  CONS1f(P2,2)  CONS1f(P3,3)
        CONS1f(P4,4)  CONS1f(P5,5)  CONS1f(P6,6)  CONS1f(P7,7)
        CONS1f(P8,8)  CONS1f(P9,9)  CONS1f(P10,10) CONS1f(P11,11)
        CONS1f(P12,12) CONS1f(P13,13) CONS1f(P14,14) CONS1f(P15,15)
        float g = acc0 + acc1 + pre2v + (t ? bc_r : bias_r);
        if (t) {                          // wgt-half: 32 dot2 from row tid (conflict-free)
            const uint2* er = (const uint2*)(s_encW + tid * 34);
            const uint2* wg = (const uint2*)s_wgt2;
            float w0 = 0.f, w1 = 0.f;
#pragma unroll
            for (int j = 0; j < 16; ++j) {
                uint2 ew = er[j], ww = wg[j];
                w0 = fdot2(ew.x, ww.x, w0);
                w1 = fdot2(ew.y, ww.y, w1);
            }
            g += w0 + w1;
        }
        // LSTM pointwise IN-QUAD: lanes 4m..4m+3 hold gates (i,f,g,o) of h_m
        {
            float gi = __shfl(g, qb + 0);
            float gf = __shfl(g, qb + 1);
            float gg = __shfl(g, qb + 2);
            float go = __shfl(g, qb + 3);
            float c = sigm(gf) * c_reg + sigm(gi) * tanh_fast(gg);
            c_reg = c;
            float h = sigm(go) * tanh_fast(c);
            if ((tid & 3) == 0) hwp0[(size_t)t * 192 + m] = h;
            float h_p = __shfl(h, lane ^ 4);          // partner quad's h
            if ((tid & 7) == 0) s_h2[tid >> 3] = packh(h, h_p);  // (h_2k, h_2k+1)
        }
        SYNC();                          // (2) h(t) ready (packed)
        // att_h[a] = h @ W2a[:,a] + bh2a[a] : 8-lane group per a, 8 dot2/lane
        {
            int a = tid >> 3, sub = tid & 7;
            const uint4* hv = (const uint4*)s_h2;
            uint4 hA = hv[2 * sub], hB = hv[2 * sub + 1];
            const uint4* wr = (const uint4*)(s_w2aTp + a * 68 + 8 * sub);
            uint4 wA = wr[0], wB = wr[1];
            float a0 = 0.f, a1 = 0.f;
            a0 = fdot2(wA.x, hA.x, a0);  a1 = fdot2(wA.y, hA.y, a1);
            a0 = fdot2(wA.z, hA.z, a0);  a1 = fdot2(wA.w, hA.w, a1);
            a0 = fdot2(wB.x, hB.x, a0);  a1 = fdot2(wB.y, hB.y, a1);
            a0 = fdot2(wB.z, hB.z, a0);  a1 = fdot2(wB.w, hB.w, a1);
            float acc = a0 + a1;
            acc += __shfl_xor(acc, 1);
            acc += __shfl_xor(acc, 2);
            acc += __shfl_xor(acc, 4);
            if (sub == 0) s_atth[a] = acc + s_bh2a[a];
        }
        SYNC();                          // (3) atth ready
        // scores[s] = sum_a tanh(p_enc + att_h) * W_alpha : 8 lanes per s
        {
            int ss = tid >> 3, sub = tid & 7;
            float acc = 0.f;
#pragma unroll
            for (int j = 0; j < 8; ++j) {
                int a = sub * 8 + j;
                float xv = s_penc[ss * 65 + a] + s_atth[a];
                acc += tanh_fast(xv) * s_walpha[a];
            }
            acc += __shfl_xor(acc, 1);
            acc += __shfl_xor(acc, 2);
            acc += __shfl_xor(acc, 4);
            if (sub == 0) s_scores[ss] = acc + bal;
        }
        SYNC();                          // (4) scores ready
        if (tid < 64) {                  // softmax → wgt packed (+ f32 to g_hw for kD)
            float v = s_scores[tid];
            float mx = v;
#pragma unroll
            for (int off = 32; off > 0; off >>= 1) mx = fmaxf(mx, __shfl_xor(mx, off));
            float e = __expf(v - mx);
            float sum = e;
#pragma unroll
            for (int off = 32; off > 0; off >>= 1) sum += __shfl_xor(sum, off);
            float w = e / sum;
            hwp0[(size_t)t * 192 + 128 + tid] = w;
            float w_p = __shfl(w, lane ^ 1);
            if ((tid & 1) == 0) s_wgt2[tid >> 1] = packh(w, w_p);
        }
        // loop-top SYNC covers s_wgt2/s_h2 reuse
    }
}

// ---- D: out = h@Wao_h + wgt@encWao[b] + bao ----
__global__ void kD(float* __restrict__ out) {
    int r = blockIdx.x * 4 + (threadIdx.x >> 6);
    int lane = threadIdx.x & 63;
    int b = r / TDIM;
    float acc[5] = {0.f, 0.f, 0.f, 0.f, 0.f};
    if (lane < 48) {
        const float4* hv = (const float4*)(g_hw + (size_t)r * 192);
        float4 v = hv[lane];
        int k0 = lane * 4;
        if (lane < 32) {
#pragma unroll
            for (int o = 0; o < 5; ++o)
                acc[o] = v.x * g_Wao[(k0 + 0) * 5 + o] + v.y * g_Wao[(k0 + 1) * 5 + o] +
                         v.z * g_Wao[(k0 + 2) * 5 + o] + v.w * g_Wao[(k0 + 3) * 5 + o];
        } else {
            int s0 = k0 - 128;
            const float* ew = g_encWao + ((size_t)b * 64 + s0) * 5;
#pragma unroll
            for (int o = 0; o < 5; ++o)
                acc[o] = v.x * ew[o] + v.y * ew[5 + o] + v.z * ew[10 + o] + v.w * ew[15 + o];
        }
    }
#pragma unroll
    for (int off = 32; off > 0; off >>= 1) {
#pragma unroll
        for (int o = 0; o < 5; ++o) acc[o] += __shfl_xor(acc[o], off);
    }
    if (lane == 0) {
#pragma unroll
        for (int o = 0; o < 5; ++o) out[(size_t)r * 5 + o] = acc[o] + g_bao[o];
    }
}

extern "C" void kernel_launch(void* const* d_in, const int* in_sizes, int n_in,
                              void* d_out, int out_size, void* d_ws, size_t ws_size,
                              hipStream_t stream) {
    (void)in_sizes; (void)n_in; (void)d_ws; (void)ws_size; (void)out_size;
    const float* tok  = (const float*)d_in[0];
    const float* feat = (const float*)d_in[1];
    const float* FH   = (const float*)d_in[2];
    const float* Wemb = (const float*)d_in[3];
    const float* bemb = (const float*)d_in[4];
    const float* Wih  = (const float*)d_in[5];
    const float* bih  = (const float*)d_in[6];
    const float* Whh  = (const float*)d_in[7];
    const float* bhh  = (const float*)d_in[8];
    const float* W2a  = (const float*)d_in[9];
    const float* bh2a = (const float*)d_in[10];
    const float* Wal  = (const float*)d_in[11];
    const float* bal  = (const float*)d_in[12];
    const float* Wep  = (const float*)d_in[13];
    const float* bep  = (const float*)d_in[14];
    const float* Waap = (const float*)d_in[15];
    const float* baap = (const float*)d_in[16];
    const float* Wout = (const float*)d_in[17];
    const float* bout = (const float*)d_in[18];
    float* out = (float*)d_out;

    const int kc_dyn_lds = 69632 + 16640 + 17408;    // 103680 B
    (void)hipFuncSetAttribute((const void*)kC,
                              hipFuncAttributeMaxDynamicSharedMemorySize,
                              kc_dyn_lds);

    kA1<<<dim3(BT / 4), dim3(256), 0, stream>>>(tok, feat, Wemb, bemb);
    kA2a<<<dim3(128), dim3(512), 0, stream>>>(Wih, Whh, Waap);
    kA2c<<<dim3(1), dim3(512), 0, stream>>>(bih, bhh, Wih, Waap, baap, Wout, bout);
    kA2d<<<dim3(64), dim3(256), 0, stream>>>(FH, Wep, bep);
    kA2e<<<dim3(BDIM), dim3(512), 0, stream>>>(FH);
    kB<<<dim3(BT / 8), dim3(512), 0, stream>>>(Wih);
    kC<<<dim3(64), dim3(512), kc_dyn_lds, stream>>>(Wal, bal, bh2a, W2a);
    kD<<<dim3(BT / 4), dim3(256), 0, stream>>>(out);
}